// Round 3
// baseline (12764.601 us; speedup 1.0000x reference)
//
#include <hip/hip_runtime.h>
#include <hip/hip_bf16.h>
#include <cmath>

// ---------------- types & helpers ----------------
typedef __attribute__((ext_vector_type(8))) short short8;   // 8 bf16 in 4 VGPRs
typedef __attribute__((ext_vector_type(4))) float f32x4;

__device__ inline float bf2f(ushort u) {
    unsigned v = (unsigned)u << 16; float f; __builtin_memcpy(&f, &v, 4); return f;
}
__device__ inline ushort f2bf(float f) {
    __hip_bfloat16 h = __float2bfloat16(f); ushort u; __builtin_memcpy(&u, &h, 2); return u;
}
__device__ inline float sigf(float z) { return 1.f / (1.f + expf(-z)); }

// dims
#define BB 256   // batch
#define LL 256   // seq len
#define HH 512   // hidden = C
#define G4 2048  // 4*H

// ---------------- prologue kernels ----------------

// zero h_prev (bf16) and C state (fp32); 131072 elements each, grid 512x256
__global__ __launch_bounds__(256) void init_state(ushort* hp, float* Cst) {
    int i = blockIdx.x * 256 + threadIdx.x;
    hp[i] = 0; Cst[i] = 0.f;
}

// out[n][k] = (bf16) in[k][n] ; in fp32 [K][N], out bf16 [N][K]; grid (K/32, N/32), 256 thr
__global__ __launch_bounds__(256) void transpose_f32_bf16(
    const float* __restrict__ in, ushort* __restrict__ out, int K, int N)
{
    __shared__ float tile[32][33];
    int tx = threadIdx.x & 31, ty = threadIdx.x >> 5;   // ty 0..7
    int bk = blockIdx.x * 32, bn = blockIdx.y * 32;
    #pragma unroll
    for (int i = 0; i < 32; i += 8)
        tile[ty + i][tx] = in[(size_t)(bk + ty + i) * N + (bn + tx)];
    __syncthreads();
    #pragma unroll
    for (int i = 0; i < 32; i += 8)
        out[(size_t)(bn + ty + i) * K + (bk + tx)] = f2bf(tile[tx][ty + i]);
}

// out[k][n] = (use_base? base[k][n] : 0) + sum_m A[k][m] * Bm[m][n]
// A fp32 [512][512], Bm fp32 [512][2048], out fp32 [512][2048]
// grid (2048/256=8, 512/8=64), 256 thr
__global__ __launch_bounds__(256) void combine_w(
    const float* __restrict__ base, const float* __restrict__ A,
    const float* __restrict__ Bm, float* __restrict__ out, int use_base)
{
    int n  = blockIdx.x * 256 + threadIdx.x;
    int k0 = blockIdx.y * 8;
    float acc[8];
    #pragma unroll
    for (int r = 0; r < 8; ++r)
        acc[r] = use_base ? base[(size_t)(k0 + r) * G4 + n] : 0.f;
    for (int m = 0; m < 512; ++m) {
        float bv = Bm[(size_t)m * G4 + n];
        #pragma unroll
        for (int r = 0; r < 8; ++r)
            acc[r] = fmaf(A[(size_t)(k0 + r) * 512 + m], bv, acc[r]);
    }
    #pragma unroll
    for (int r = 0; r < 8; ++r) out[(size_t)(k0 + r) * G4 + n] = acc[r];
}

// bias_g[n] = Wih_b[n] + Whm_b[n] + sum_m (Wmx_b[m]+Wmh_b[m]) * Whm[m][n]; grid 8 x 256
__global__ __launch_bounds__(256) void bias_g_kernel(
    const float* __restrict__ Wih_b, const float* __restrict__ Whm_b,
    const float* __restrict__ Wmx_b, const float* __restrict__ Wmh_b,
    const float* __restrict__ Whm, float* __restrict__ bias_g)
{
    int n = blockIdx.x * 256 + threadIdx.x;
    float acc = Wih_b[n] + Whm_b[n];
    for (int m = 0; m < 512; ++m)
        acc = fmaf(Wmx_b[m] + Wmh_b[m], Whm[(size_t)m * G4 + n], acc);
    bias_g[n] = acc;
}

// ---------------- per-step stage kernels ----------------

// out[b][j] = bf16( 2*sigmoid( sum_k A[b][k]*WT[j][k] ) * scale[b][j] )
// A bf16 [256][512]; WT bf16 [512][512] (row j = output col, contiguous K)
// scale: either bf16 [256][512] (scaleB) or fp32 with row stride (scaleF)
// grid (256/32=8, 512/32=16), 256 thr (4 waves, 2x2 of 16x16 tiles)
__global__ __launch_bounds__(256) void mog_stage(
    const ushort* __restrict__ A, const ushort* __restrict__ WT,
    const ushort* __restrict__ scaleB, const float* __restrict__ scaleF,
    long scaleF_stride, ushort* __restrict__ out)
{
    int lane = threadIdx.x & 63;
    int wave = threadIdx.x >> 6;
    int row0 = blockIdx.x * 32 + (wave >> 1) * 16;
    int col0 = blockIdx.y * 32 + (wave & 1) * 16;
    int lr = lane & 15, lk = lane >> 4;     // lk = k-group 0..3

    const short8* Ap = (const short8*)(A  + (size_t)(row0 + lr) * HH);
    const short8* Wp = (const short8*)(WT + (size_t)(col0 + lr) * HH);
    f32x4 acc = {0.f, 0.f, 0.f, 0.f};
    #pragma unroll
    for (int kk = 0; kk < 16; ++kk) {
        short8 a = Ap[kk * 4 + lk];   // A[row][k0 + lk*8 .. +8]
        short8 b = Wp[kk * 4 + lk];   // WT[col][k0 + lk*8 .. +8]
        acc = __builtin_amdgcn_mfma_f32_16x16x32_bf16(a, b, acc, 0, 0, 0);
    }
    #pragma unroll
    for (int r = 0; r < 4; ++r) {
        int row = row0 + lk * 4 + r;       // C/D layout: col=lane&15, row=(lane>>4)*4+r
        int col = col0 + lr;
        float s = 2.f * sigf(acc[r]);
        float xv = scaleF ? scaleF[(size_t)row * scaleF_stride + col]
                          : bf2f(scaleB[(size_t)row * HH + col]);
        out[(size_t)row * HH + col] = f2bf(s * xv);
    }
}

// gates = X3 @ W1 + H2 @ W2 + bias; then LSTM cell elementwise; writes h (bf16 + fp32 out)
// W1T/W2T bf16 [2048][512]. Block: rows r0..r0+32, h-cols c0..c0+32; wave q = gate quadrant.
// grid (8, 16), 256 thr
__global__ __launch_bounds__(256) void gates_lstm(
    const ushort* __restrict__ X3, const ushort* __restrict__ H2,
    const ushort* __restrict__ W1T, const ushort* __restrict__ W2T,
    const float* __restrict__ biasg, float* __restrict__ Cst,
    ushort* __restrict__ Hb, float* __restrict__ outF, long out_stride)
{
    __shared__ float gq[4][32][32];
    int lane = threadIdx.x & 63;
    int q = threadIdx.x >> 6;           // wave index = gate quadrant (i,f,g,o)
    int r0 = blockIdx.x * 32;
    int c0 = blockIdx.y * 32;
    int lr = lane & 15, lk = lane >> 4;

    f32x4 a00 = {0,0,0,0}, a01 = {0,0,0,0}, a10 = {0,0,0,0}, a11 = {0,0,0,0};

    {   // X3 @ W1T
        const short8* A0 = (const short8*)(X3 + (size_t)(r0 + lr) * HH);
        const short8* A1 = (const short8*)(X3 + (size_t)(r0 + 16 + lr) * HH);
        const short8* B0 = (const short8*)(W1T + (size_t)(q * 512 + c0 + lr) * HH);
        const short8* B1 = (const short8*)(W1T + (size_t)(q * 512 + c0 + 16 + lr) * HH);
        #pragma unroll
        for (int kk = 0; kk < 16; ++kk) {
            short8 x0 = A0[kk * 4 + lk], x1 = A1[kk * 4 + lk];
            short8 w0 = B0[kk * 4 + lk], w1 = B1[kk * 4 + lk];
            a00 = __builtin_amdgcn_mfma_f32_16x16x32_bf16(x0, w0, a00, 0, 0, 0);
            a01 = __builtin_amdgcn_mfma_f32_16x16x32_bf16(x0, w1, a01, 0, 0, 0);
            a10 = __builtin_amdgcn_mfma_f32_16x16x32_bf16(x1, w0, a10, 0, 0, 0);
            a11 = __builtin_amdgcn_mfma_f32_16x16x32_bf16(x1, w1, a11, 0, 0, 0);
        }
    }
    {   // + H2 @ W2T
        const short8* A0 = (const short8*)(H2 + (size_t)(r0 + lr) * HH);
        const short8* A1 = (const short8*)(H2 + (size_t)(r0 + 16 + lr) * HH);
        const short8* B0 = (const short8*)(W2T + (size_t)(q * 512 + c0 + lr) * HH);
        const short8* B1 = (const short8*)(W2T + (size_t)(q * 512 + c0 + 16 + lr) * HH);
        #pragma unroll
        for (int kk = 0; kk < 16; ++kk) {
            short8 x0 = A0[kk * 4 + lk], x1 = A1[kk * 4 + lk];
            short8 w0 = B0[kk * 4 + lk], w1 = B1[kk * 4 + lk];
            a00 = __builtin_amdgcn_mfma_f32_16x16x32_bf16(x0, w0, a00, 0, 0, 0);
            a01 = __builtin_amdgcn_mfma_f32_16x16x32_bf16(x0, w1, a01, 0, 0, 0);
            a10 = __builtin_amdgcn_mfma_f32_16x16x32_bf16(x1, w0, a10, 0, 0, 0);
            a11 = __builtin_amdgcn_mfma_f32_16x16x32_bf16(x1, w1, a11, 0, 0, 0);
        }
    }

    // stage quadrant to LDS (+bias)
    #pragma unroll
    for (int r = 0; r < 4; ++r) {
        gq[q][lk * 4 + r     ][lr     ] = a00[r] + biasg[q * 512 + c0 + lr];
        gq[q][lk * 4 + r     ][lr + 16] = a01[r] + biasg[q * 512 + c0 + lr + 16];
        gq[q][lk * 4 + r + 16][lr     ] = a10[r] + biasg[q * 512 + c0 + lr];
        gq[q][lk * 4 + r + 16][lr + 16] = a11[r] + biasg[q * 512 + c0 + lr + 16];
    }
    __syncthreads();

    // LSTM elementwise: 1024 elems over 256 threads
    #pragma unroll
    for (int e = 0; e < 4; ++e) {
        int idx = e * 256 + threadIdx.x;
        int rl = idx >> 5, cl = idx & 31;
        float ig = sigf(gq[0][rl][cl]);
        float fg = sigf(gq[1][rl][cl]);
        float cg = tanhf(gq[2][rl][cl]);
        float og = sigf(gq[3][rl][cl]);
        size_t gi = (size_t)(r0 + rl) * HH + (c0 + cl);
        float C = Cst[gi];
        C = fg * C + ig * cg;
        Cst[gi] = C;
        float h = og * tanhf(C);
        Hb[gi] = f2bf(h);
        outF[(size_t)(r0 + rl) * out_stride + (c0 + cl)] = h;
    }
}

// ---------------- host launcher ----------------
extern "C" void kernel_launch(void* const* d_in, const int* in_sizes, int n_in,
                              void* d_out, int out_size, void* d_ws, size_t ws_size,
                              hipStream_t stream)
{
    const float* x     = (const float*)d_in[0];   // (256,256,512)
    const float* Wih_w = (const float*)d_in[1];   // (512,2048)
    const float* Wih_b = (const float*)d_in[2];   // (2048)
    const float* Wmx_w = (const float*)d_in[3];   // (512,512)
    const float* Wmx_b = (const float*)d_in[4];   // (512)
    const float* Wmh_w = (const float*)d_in[5];   // (512,512)
    const float* Wmh_b = (const float*)d_in[6];   // (512)
    const float* Whm_w = (const float*)d_in[7];   // (512,2048)
    const float* Whm_b = (const float*)d_in[8];   // (2048)
    const float* Q     = (const float*)d_in[9];   // (512,512)  h -> c
    const float* R     = (const float*)d_in[10];  // (512,512)  x -> h
    float* out = (float*)d_out;                   // (256,256,512)

    char* ws = (char*)d_ws;
    ushort* QT   = (ushort*)ws;               ws += (size_t)512 * 512 * 2;      // bf16 [512][512]
    ushort* RT   = (ushort*)ws;               ws += (size_t)512 * 512 * 2;
    ushort* W1T  = (ushort*)ws;               ws += (size_t)G4  * 512 * 2;      // bf16 [2048][512]
    ushort* W2T  = (ushort*)ws;               ws += (size_t)G4  * 512 * 2;
    float*  biasg= (float*)ws;                ws += (size_t)G4 * 4;
    ushort* xa   = (ushort*)ws;               ws += (size_t)BB * HH * 2;
    ushort* xb   = (ushort*)ws;               ws += (size_t)BB * HH * 2;
    ushort* hp   = (ushort*)ws;               ws += (size_t)BB * HH * 2;
    ushort* hq   = (ushort*)ws;               ws += (size_t)BB * HH * 2;
    ushort* hr   = (ushort*)ws;               ws += (size_t)BB * HH * 2;
    float*  Cst  = (float*)ws;                ws += (size_t)BB * HH * 4;
    float*  Wtmp = (float*)ws;                ws += (size_t)512 * G4 * 4;       // fp32 [512][2048]

    // prologue: state init + weight prep (all on stream, graph-capture safe)
    init_state<<<512, 256, 0, stream>>>(hp, Cst);
    transpose_f32_bf16<<<dim3(16, 16), 256, 0, stream>>>(Q, QT, 512, 512);
    transpose_f32_bf16<<<dim3(16, 16), 256, 0, stream>>>(R, RT, 512, 512);
    combine_w<<<dim3(8, 64), 256, 0, stream>>>(Wih_w, Wmx_w, Whm_w, Wtmp, 1);   // W1 = Wih + Wmx@Whm
    transpose_f32_bf16<<<dim3(16, 64), 256, 0, stream>>>(Wtmp, W1T, 512, G4);
    combine_w<<<dim3(8, 64), 256, 0, stream>>>(nullptr, Wmh_w, Whm_w, Wtmp, 0); // W2 = Wmh@Whm
    transpose_f32_bf16<<<dim3(16, 64), 256, 0, stream>>>(Wtmp, W2T, 512, G4);
    bias_g_kernel<<<8, 256, 0, stream>>>(Wih_b, Whm_b, Wmx_b, Wmh_b, Whm_w, biasg);

    dim3 sgrid(8, 16);
    const long xstride = (long)LL * HH;   // 131072
    for (int t = 0; t < LL; ++t) {
        const float* xt = x + (size_t)t * HH;
        // S1: x1 = 2*sig(h_prev @ Q) * x_t          -> xa
        mog_stage<<<sgrid, 256, 0, stream>>>(hp, QT, nullptr, xt, xstride, xa);
        // S2: h1 = 2*sig(x1 @ R) * h_prev           -> hq
        mog_stage<<<sgrid, 256, 0, stream>>>(xa, RT, hp, nullptr, 0, hq);
        // S3: x2 = 2*sig(h1 @ Q) * x1               -> xb
        mog_stage<<<sgrid, 256, 0, stream>>>(hq, QT, xa, nullptr, 0, xb);
        // S4: h2 = 2*sig(x2 @ R) * h1               -> hr
        mog_stage<<<sgrid, 256, 0, stream>>>(xb, RT, hq, nullptr, 0, hr);
        // S5: x3 = 2*sig(h2 @ Q) * x2               -> xa (x1 dead after S3)
        mog_stage<<<sgrid, 256, 0, stream>>>(hr, QT, xb, nullptr, 0, xa);
        // S6: gates + LSTM cell; h_t -> hp (next step's h_prev) + d_out[:,t,:]
        gates_lstm<<<sgrid, 256, 0, stream>>>(xa, hr, W1T, W2T, biasg, Cst, hp,
                                              out + (size_t)t * HH, xstride);
    }
}